// Round 5
// baseline (252.884 us; speedup 1.0000x reference)
//
#include <hip/hip_runtime.h>
#include <math.h>

#define EPS 1e-5f
#define FD 8192

typedef __attribute__((ext_vector_type(8))) __bf16 bf16x8;
typedef __attribute__((ext_vector_type(4))) float f32x4;

static __device__ __forceinline__ f32x4 mfma16(bf16x8 a, bf16x8 b, f32x4 c) {
    return __builtin_amdgcn_mfma_f32_16x16x32_bf16(a, b, c, 0, 0, 0);
}

// ============ K0: tiny frag prep for conv weights (19 blocks) ================
__global__ __launch_bounds__(256) void k_prep_frags(
    const float* __restrict__ w1, const float* __restrict__ w2,
    __bf16* __restrict__ w1frag, __bf16* __restrict__ w2frag) {
    const int bb = blockIdx.x, t = threadIdx.x;
    if (bb == 0) {
        const int lane = t & 63, w = t >> 6;
        const int q = lane >> 4, li = lane & 15;
        const int o = w * 16 + li;
        bf16x8 v;
#pragma unroll
        for (int j = 0; j < 8; ++j) {
            int k = q * 8 + j;
            v[j] = (k < 9) ? (__bf16)w1[o * 9 + k] : (__bf16)0.0f;
        }
        *(bf16x8*)(w1frag + t * 8) = v;
    } else {
        const int id = (bb - 1) * 256 + t;
        const int lane = id & 63;
        const int w = (id >> 6) & 3;
        const int chunk = (id >> 8) & 1;
        const int tap = id >> 9;
        const int q = lane >> 4, li = lane & 15;
        const int o = w * 16 + li;
        const int c0 = chunk * 32 + q * 8;
        bf16x8 v;
#pragma unroll
        for (int j = 0; j < 8; ++j)
            v[j] = (__bf16)w2[(o * 64 + c0 + j) * 9 + tap];
        *(bf16x8*)(w2frag + (size_t)id * 8) = v;
    }
}

// ========== K1: conv stage (blocks 0..1535) + big weight preps (1536..3519) ==
// prep blocks overlap with conv compute in the same dispatch.
__global__ __launch_bounds__(256) void k_conv_mega(
    const float* __restrict__ inA, const float* __restrict__ inP, const float* __restrict__ inN,
    const float* __restrict__ bn0g, const float* __restrict__ bn0b,
    const float* __restrict__ bn0m, const float* __restrict__ bn0v,
    const __bf16* __restrict__ w1frag, const float* __restrict__ b1,
    const float* __restrict__ bn1g, const float* __restrict__ bn1b,
    const float* __restrict__ bn1m, const float* __restrict__ bn1v,
    const __bf16* __restrict__ w2frag, const float* __restrict__ b2,
    const float* __restrict__ bn2g, const float* __restrict__ bn2b,
    const float* __restrict__ bn2m, const float* __restrict__ bn2v,
    __bf16* __restrict__ act,
    // prep inputs/outputs
    const float* __restrict__ lc1, const float* __restrict__ lc2,
    const float* __restrict__ fc1w, const float* __restrict__ fc2w,
    const float* __restrict__ fc3w, const float* __restrict__ outw,
    __bf16* __restrict__ lc1frag, __bf16* __restrict__ lc2frag,
    __bf16* __restrict__ fc1Wb, __bf16* __restrict__ wf23) {
    const int bb = blockIdx.x;
    const int t = threadIdx.x;
    __shared__ __align__(16) char smem[43136];

    if (bb >= 1536) {
        const int pb = bb - 1536;
        float (*wbuf)[130] = (float(*)[130])smem;
        if (pb < 128) {
            // lc weights -> frag order (block per (layer,o))
            const int layer = pb >> 6, o = pb & 63;
            const int wo = o >> 4, lo = o & 15;
            const float* src = (layer ? lc2 : lc1) + (size_t)o * 8192;
            __bf16* dst = layer ? lc2frag : lc1frag;
#pragma unroll
            for (int pass = 0; pass < 8; ++pass) {
                int i = pass * 1024 + t * 4;
                float4 v = *(const float4*)(src + i);
                int c = i >> 7, p = i & 127;
                wbuf[c][p + 0] = v.x; wbuf[c][p + 1] = v.y;
                wbuf[c][p + 2] = v.z; wbuf[c][p + 3] = v.w;
            }
            __syncthreads();
#pragma unroll
            for (int pass = 0; pass < 4; ++pass) {
                int slot = pass * 256 + t;
                int p = slot >> 3, chunk = (slot >> 2) & 1, q = slot & 3;
                bf16x8 v;
#pragma unroll
                for (int j = 0; j < 8; ++j)
                    v[j] = (__bf16)wbuf[chunk * 32 + q * 8 + j][p];
                *(bf16x8*)(dst + ((size_t)((p * 2 + chunk) * 4 + wo) * 64 + q * 16 + lo) * 8) = v;
            }
        } else if (pb < 640) {
            // fc1 weights -> bf16 [n][kA], kA = p*64+c
            const int n = pb - 128;
            const float* src = fc1w + (size_t)n * 8192;
            __bf16* dst = fc1Wb + (size_t)n * 8192;
#pragma unroll
            for (int pass = 0; pass < 8; ++pass) {
                int i = pass * 1024 + t * 4;
                float4 v = *(const float4*)(src + i);
                int c = i >> 7, p = i & 127;
                wbuf[c][p + 0] = v.x; wbuf[c][p + 1] = v.y;
                wbuf[c][p + 2] = v.z; wbuf[c][p + 3] = v.w;
            }
            __syncthreads();
#pragma unroll
            for (int pass = 0; pass < 16; ++pass) {
                int kA = (pass * 256 + t) * 2;
                int c = kA & 63, p = kA >> 6;
                __bf16 tmp[2];
                tmp[0] = (__bf16)wbuf[c][p];
                tmp[1] = (__bf16)wbuf[c + 1][p];
                *(unsigned int*)(dst + kA) = *(unsigned int*)tmp;
            }
        } else {
            // cast fc2/fc3/out weights to bf16
            int i = (pb - 640) * 256 + t;
            float v;
            if (i < 262144) v = fc2w[i];
            else if (i < 327680) v = fc3w[i - 262144];
            else v = outw[i - 327680];
            wf23[i] = (__bf16)v;
        }
        return;
    }

    // ---------------- conv path ----------------
    const int b = bb;
    const int lane = t & 63, w = t >> 6;
    const int q = lane >> 4, li = lane & 15;
    const int n0 = w * 16;
    const float* src = (b < 512 ? inA : (b < 1024 ? inP : inN)) + (size_t)(b & 511) * 128;

    float* xpad = (float*)smem;                         // 180 f (720 B, pad 768)
    __bf16* A1 = (__bf16*)(smem + 768);                 // 128*40 bf16 (10240 B)
    __bf16* Xp = (__bf16*)(smem + 11008);               // 18*12*72 bf16 (31104 B)
    float* s1 = (float*)(smem + 42112);
    float* sh1 = (float*)(smem + 42368);
    float* s2 = (float*)(smem + 42624);
    float* sh2 = (float*)(smem + 42880);

    bf16x8 w1f = *(const bf16x8*)(w1frag + (size_t)(w * 64 + lane) * 8);
    bf16x8 w2f[18];
#pragma unroll
    for (int tap = 0; tap < 9; ++tap)
#pragma unroll
        for (int ch = 0; ch < 2; ++ch)
            w2f[tap * 2 + ch] = *(const bf16x8*)(w2frag +
                ((size_t)((tap * 2 + ch) * 4 + w) * 64 + lane) * 8);

    {
        int* xz = (int*)Xp;
        for (int i = t; i < 7776; i += 256) xz[i] = 0;
        if (t < 180) xpad[t] = 0.f;
        if (t < 64) {
            float sa = bn1g[t] * rsqrtf(bn1v[t] + EPS);
            s1[t] = sa;
            sh1[t] = (b1[t] - bn1m[t]) * sa + bn1b[t];
            float sb = bn2g[t] * rsqrtf(bn2v[t] + EPS);
            s2[t] = sb;
            sh2[t] = (b2[t] - bn2m[t]) * sb + bn2b[t];
        }
    }
    __syncthreads();
    if (t < 128) {
        float s0 = bn0g[0] * rsqrtf(bn0v[0] + EPS);
        float v = (src[t] - bn0m[0]) * s0 + bn0b[0];
        xpad[((t >> 3) + 1) * 10 + (t & 7) + 1] = v;
    }
    __syncthreads();
    {   // im2col A1[p][k], b128 writes
        int p = t >> 1, half = t & 1;
        int r = p >> 3, cl = p & 7;
        bf16x8 v0, v1;
#pragma unroll
        for (int jj = 0; jj < 8; ++jj) {
            int j = half * 16 + jj;
            v0[jj] = (j < 9) ? (__bf16)xpad[(r + j / 3) * 10 + cl + (j % 3)] : (__bf16)0.f;
            int j2 = half * 16 + 8 + jj;
            v1[jj] = (j2 < 9) ? (__bf16)xpad[(r + j2 / 3) * 10 + cl + (j2 % 3)] : (__bf16)0.f;
        }
        *(bf16x8*)&A1[p * 40 + half * 16] = v0;
        *(bf16x8*)&A1[p * 40 + half * 16 + 8] = v1;
    }
    __syncthreads();
    {   // conv1 MFMA, bn1+relu -> Xp interior (c-inner)
        const float sco = s1[n0 + li], sho = sh1[n0 + li];
        const int o = n0 + li;
#pragma unroll
        for (int m = 0; m < 8; ++m) {
            bf16x8 a = *(const bf16x8*)&A1[(m * 16 + li) * 40 + q * 8];
            f32x4 z = {0.f, 0.f, 0.f, 0.f};
            f32x4 d = mfma16(a, w1f, z);
#pragma unroll
            for (int r = 0; r < 4; ++r) {
                int p = m * 16 + q * 4 + r;
                float v = fmaxf(d[r] * sco + sho, 0.f);
                Xp[(((p >> 3) + 1) * 12 + (p & 7) + 1) * 72 + o] = (__bf16)v;
            }
        }
    }
    __syncthreads();
    f32x4 accA[4], accB[4];
#pragma unroll
    for (int i = 0; i < 4; ++i) {
        accA[i] = (f32x4){0.f, 0.f, 0.f, 0.f};
        accB[i] = (f32x4){0.f, 0.f, 0.f, 0.f};
    }
    {
        const int cl = li & 7;
#pragma unroll
        for (int mp = 0; mp < 4; ++mp) {
            const int r0 = mp * 4 + (li >> 3);
            const int base0 = (r0 * 12 + cl) * 72 + q * 8;
            const int base1 = base0 + 1728;
#pragma unroll
            for (int tap = 0; tap < 9; ++tap) {
                const int tofs = ((tap / 3) * 12 + (tap % 3)) * 72;
#pragma unroll
                for (int ch = 0; ch < 2; ++ch) {
                    bf16x8 a0 = *(const bf16x8*)&Xp[base0 + tofs + ch * 32];
                    bf16x8 a1 = *(const bf16x8*)&Xp[base1 + tofs + ch * 32];
                    accA[mp] = mfma16(a0, w2f[tap * 2 + ch], accA[mp]);
                    accB[mp] = mfma16(a1, w2f[tap * 2 + ch], accB[mp]);
                }
            }
        }
    }
    __syncthreads();
    {   // bn2+relu, repack via Xp (stride 72)
        const float sco = s2[n0 + li], sho = sh2[n0 + li];
        const int o = n0 + li;
#pragma unroll
        for (int mp = 0; mp < 4; ++mp) {
#pragma unroll
            for (int r = 0; r < 4; ++r) {
                int p0 = mp * 32 + q * 4 + r;
                Xp[p0 * 72 + o] = (__bf16)fmaxf(accA[mp][r] * sco + sho, 0.f);
                Xp[(p0 + 16) * 72 + o] = (__bf16)fmaxf(accB[mp][r] * sco + sho, 0.f);
            }
        }
    }
    __syncthreads();
    {   // coalesced store: 64 B/thread
        int p = t >> 1, half = t & 1;
        const __bf16* rp = Xp + p * 72 + half * 32;
        __bf16* ob = act + (size_t)b * FD + p * 64 + half * 32;
        bf16x8 v0 = *(const bf16x8*)rp;
        bf16x8 v1 = *(const bf16x8*)(rp + 8);
        bf16x8 v2 = *(const bf16x8*)(rp + 16);
        bf16x8 v3 = *(const bf16x8*)(rp + 24);
        *(bf16x8*)ob = v0;
        *(bf16x8*)(ob + 8) = v1;
        *(bf16x8*)(ob + 16) = v2;
        *(bf16x8*)(ob + 24) = v3;
    }
}

// ========== K2: lc1 + bn3relu + lc2 + bn4relu, 128-sample tiles ==============
__global__ __launch_bounds__(256) void k_lc_mfma(
    const __bf16* __restrict__ lc1frag, const __bf16* __restrict__ lc2frag,
    const float* __restrict__ bn3g, const float* __restrict__ bn3b,
    const float* __restrict__ bn3m, const float* __restrict__ bn3v,
    const float* __restrict__ bn4g, const float* __restrict__ bn4b,
    const float* __restrict__ bn4m, const float* __restrict__ bn4v,
    __bf16* __restrict__ act) {
    const int p = blockIdx.x;
    const int b0 = blockIdx.y * 128;
    const int t = threadIdx.x;
    const int lane = t & 63, w = t >> 6;
    const int q = lane >> 4, li = lane & 15;
    const int n0 = w * 16;

    __shared__ __align__(16) __bf16 xs[128 * 72];
    __shared__ __align__(16) __bf16 ys[128 * 72];
    __shared__ float s3[64], sh3[64], s4[64], sh4[64];

    if (t < 64) {
        float sa = bn3g[t] * rsqrtf(bn3v[t] + EPS);
        s3[t] = sa; sh3[t] = bn3b[t] - bn3m[t] * sa;
        float sb = bn4g[t] * rsqrtf(bn4v[t] + EPS);
        s4[t] = sb; sh4[t] = bn4b[t] - bn4m[t] * sb;
    }
    {   // stage 128 samples x 64 ch; 64 B/thread
        int s = t >> 1, half = t & 1;
        const __bf16* rp = act + (size_t)(b0 + s) * FD + p * 64 + half * 32;
        __bf16* xp = xs + s * 72 + half * 32;
        *(bf16x8*)xp = *(const bf16x8*)rp;
        *(bf16x8*)(xp + 8) = *(const bf16x8*)(rp + 8);
        *(bf16x8*)(xp + 16) = *(const bf16x8*)(rp + 16);
        *(bf16x8*)(xp + 24) = *(const bf16x8*)(rp + 24);
    }
    bf16x8 w1a = *(const bf16x8*)(lc1frag + ((size_t)((p * 2 + 0) * 4 + w) * 64 + lane) * 8);
    bf16x8 w1b = *(const bf16x8*)(lc1frag + ((size_t)((p * 2 + 1) * 4 + w) * 64 + lane) * 8);
    bf16x8 w2a = *(const bf16x8*)(lc2frag + ((size_t)((p * 2 + 0) * 4 + w) * 64 + lane) * 8);
    bf16x8 w2b = *(const bf16x8*)(lc2frag + ((size_t)((p * 2 + 1) * 4 + w) * 64 + lane) * 8);
    __syncthreads();
    {   // layer 1 -> ys
        const float sco = s3[n0 + li], sho = sh3[n0 + li];
#pragma unroll
        for (int m = 0; m < 8; ++m) {
            bf16x8 a0 = *(const bf16x8*)&xs[(m * 16 + li) * 72 + q * 8];
            bf16x8 a1 = *(const bf16x8*)&xs[(m * 16 + li) * 72 + 32 + q * 8];
            f32x4 acc = {0.f, 0.f, 0.f, 0.f};
            acc = mfma16(a0, w1a, acc);
            acc = mfma16(a1, w1b, acc);
#pragma unroll
            for (int r = 0; r < 4; ++r) {
                int bl = m * 16 + q * 4 + r;
                ys[bl * 72 + n0 + li] = (__bf16)fmaxf(acc[r] * sco + sho, 0.f);
            }
        }
    }
    __syncthreads();
    {   // layer 2 -> xs
        const float sco = s4[n0 + li], sho = sh4[n0 + li];
#pragma unroll
        for (int m = 0; m < 8; ++m) {
            bf16x8 a0 = *(const bf16x8*)&ys[(m * 16 + li) * 72 + q * 8];
            bf16x8 a1 = *(const bf16x8*)&ys[(m * 16 + li) * 72 + 32 + q * 8];
            f32x4 acc = {0.f, 0.f, 0.f, 0.f};
            acc = mfma16(a0, w2a, acc);
            acc = mfma16(a1, w2b, acc);
#pragma unroll
            for (int r = 0; r < 4; ++r) {
                int bl = m * 16 + q * 4 + r;
                xs[bl * 72 + n0 + li] = (__bf16)fmaxf(acc[r] * sco + sho, 0.f);
            }
        }
    }
    __syncthreads();
    {   // coalesced store
        int s = t >> 1, half = t & 1;
        const __bf16* rp = xs + s * 72 + half * 32;
        __bf16* ob = act + (size_t)(b0 + s) * FD + p * 64 + half * 32;
        bf16x8 v0 = *(const bf16x8*)rp;
        bf16x8 v1 = *(const bf16x8*)(rp + 8);
        bf16x8 v2 = *(const bf16x8*)(rp + 16);
        bf16x8 v3 = *(const bf16x8*)(rp + 24);
        *(bf16x8*)ob = v0;
        *(bf16x8*)(ob + 8) = v1;
        *(bf16x8*)(ob + 16) = v2;
        *(bf16x8*)(ob + 24) = v3;
    }
}

// ========== K3: fc1 MFMA 64x64 tile, BK=64, split-K 4, reg-prefetch ==========
__global__ __launch_bounds__(256) void k_fc1_mfma(
    const __bf16* __restrict__ A, const __bf16* __restrict__ Wb,
    float* __restrict__ part) {
    const int t = threadIdx.x;
    const int lane = t & 63, w = t >> 6;
    const int q = lane >> 4, li = lane & 15;
    const int m0 = blockIdx.x * 64, n0 = blockIdx.y * 64;
    const int k0 = blockIdx.z * 2048;
    const int wm = (w & 1) * 32, wn = (w >> 1) * 32;

    __shared__ __align__(16) __bf16 As[64 * 72];
    __shared__ __align__(16) __bf16 Bs[64 * 72];

    f32x4 acc[2][2];
#pragma unroll
    for (int i = 0; i < 2; ++i)
#pragma unroll
        for (int j = 0; j < 2; ++j) acc[i][j] = (f32x4){0.f, 0.f, 0.f, 0.f};

    const int row = t >> 2, qt = t & 3;
    const __bf16* Ag = A + (size_t)(m0 + row) * 8192 + k0 + qt * 16;
    const __bf16* Bg = Wb + (size_t)(n0 + row) * 8192 + k0 + qt * 16;

    bf16x8 pa0 = *(const bf16x8*)Ag;
    bf16x8 pa1 = *(const bf16x8*)(Ag + 8);
    bf16x8 pb0 = *(const bf16x8*)Bg;
    bf16x8 pb1 = *(const bf16x8*)(Bg + 8);

    for (int step = 0; step < 32; ++step) {
        *(bf16x8*)&As[row * 72 + qt * 16] = pa0;
        *(bf16x8*)&As[row * 72 + qt * 16 + 8] = pa1;
        *(bf16x8*)&Bs[row * 72 + qt * 16] = pb0;
        *(bf16x8*)&Bs[row * 72 + qt * 16 + 8] = pb1;
        __syncthreads();
        Ag += 64; Bg += 64;
        if (step < 31) {
            pa0 = *(const bf16x8*)Ag;
            pa1 = *(const bf16x8*)(Ag + 8);
            pb0 = *(const bf16x8*)Bg;
            pb1 = *(const bf16x8*)(Bg + 8);
        }
#pragma unroll
        for (int kc = 0; kc < 2; ++kc) {
            bf16x8 af[2], bfr[2];
#pragma unroll
            for (int i = 0; i < 2; ++i)
                af[i] = *(const bf16x8*)&As[(wm + i * 16 + li) * 72 + kc * 32 + q * 8];
#pragma unroll
            for (int j = 0; j < 2; ++j)
                bfr[j] = *(const bf16x8*)&Bs[(wn + j * 16 + li) * 72 + kc * 32 + q * 8];
#pragma unroll
            for (int i = 0; i < 2; ++i)
#pragma unroll
                for (int j = 0; j < 2; ++j)
                    acc[i][j] = mfma16(af[i], bfr[j], acc[i][j]);
        }
        __syncthreads();
    }
    float* pp = part + (size_t)blockIdx.z * 786432;
#pragma unroll
    for (int i = 0; i < 2; ++i) {
#pragma unroll
        for (int r = 0; r < 4; ++r) {
            int m = m0 + wm + i * 16 + q * 4 + r;
#pragma unroll
            for (int j = 0; j < 2; ++j) {
                int n = n0 + wn + j * 16 + li;
                pp[(size_t)m * 512 + n] = acc[i][j][r];
            }
        }
    }
}

// reduce 4 partials + bias + bn + relu -> bf16 act3
__global__ void k_fc1_reduce(const float* __restrict__ part, const float* __restrict__ bias,
                             const float* __restrict__ g, const float* __restrict__ bb,
                             const float* __restrict__ mm, const float* __restrict__ vv,
                             __bf16* __restrict__ out) {
    int gi = blockIdx.x * 256 + threadIdx.x;
    size_t off = (size_t)gi * 4;
    float4 s = make_float4(0.f, 0.f, 0.f, 0.f);
#pragma unroll
    for (int z = 0; z < 4; ++z) {
        float4 v = *(const float4*)(part + (size_t)z * 786432 + off);
        s.x += v.x; s.y += v.y; s.z += v.z; s.w += v.w;
    }
    int n = (gi & 127) * 4;
    float r[4] = {s.x, s.y, s.z, s.w};
    __bf16 o4[4];
#pragma unroll
    for (int j = 0; j < 4; ++j) {
        float sc = g[n + j] * rsqrtf(vv[n + j] + EPS);
        float x = (r[j] + bias[n + j] - mm[n + j]) * sc + bb[n + j];
        o4[j] = (__bf16)fmaxf(x, 0.f);
    }
    *(uint2*)(out + off) = *(uint2*)o4;
}

// ========= fc2: bf16 MFMA GEMM 64x64, fused bias/bn/relu, reg-prefetch =======
__global__ __launch_bounds__(256) void k_fc2_mfma(
    const __bf16* __restrict__ A, const __bf16* __restrict__ W,
    const float* __restrict__ bias,
    const float* __restrict__ bng, const float* __restrict__ bnb,
    const float* __restrict__ bnm, const float* __restrict__ bnv,
    __bf16* __restrict__ out) {
    const int t = threadIdx.x;
    const int lane = t & 63, w = t >> 6;
    const int q = lane >> 4, li = lane & 15;
    const int m0 = blockIdx.x * 64, n0 = blockIdx.y * 64;
    const int wm = (w & 1) * 32, wn = (w >> 1) * 32;
    const int K = 512, N = 512;

    __shared__ __align__(16) __bf16 As[64 * 40];
    __shared__ __align__(16) __bf16 Bs[64 * 40];

    f32x4 acc[2][2];
#pragma unroll
    for (int i = 0; i < 2; ++i)
#pragma unroll
        for (int j = 0; j < 2; ++j) acc[i][j] = (f32x4){0.f, 0.f, 0.f, 0.f};

    const int row = (t & 127) >> 1, half = t & 1;
    const __bf16* g = (t < 128 ? A + (size_t)(m0 + row) * K
                               : W + (size_t)(n0 + row) * K) + half * 16;
    __bf16* ld = (t < 128 ? As : Bs) + row * 40 + half * 16;

    bf16x8 p0 = *(const bf16x8*)g;
    bf16x8 p1 = *(const bf16x8*)(g + 8);
    for (int k0 = 0; k0 < K; k0 += 32) {
        *(bf16x8*)ld = p0;
        *(bf16x8*)(ld + 8) = p1;
        __syncthreads();
        g += 32;
        if (k0 + 32 < K) {
            p0 = *(const bf16x8*)g;
            p1 = *(const bf16x8*)(g + 8);
        }
        bf16x8 af[2], bfr[2];
#pragma unroll
        for (int i = 0; i < 2; ++i)
            af[i] = *(const bf16x8*)&As[(wm + i * 16 + li) * 40 + q * 8];
#pragma unroll
        for (int j = 0; j < 2; ++j)
            bfr[j] = *(const bf16x8*)&Bs[(wn + j * 16 + li) * 40 + q * 8];
#pragma unroll
        for (int i = 0; i < 2; ++i)
#pragma unroll
            for (int j = 0; j < 2; ++j)
                acc[i][j] = mfma16(af[i], bfr[j], acc[i][j]);
        __syncthreads();
    }
    float bi[2], sc[2], hh[2];
#pragma unroll
    for (int j = 0; j < 2; ++j) {
        int n = n0 + wn + j * 16 + li;
        bi[j] = bias[n];
        sc[j] = bng[n] * rsqrtf(bnv[n] + EPS);
        hh[j] = bnb[n] - bnm[n] * sc[j];
    }
#pragma unroll
    for (int i = 0; i < 2; ++i) {
#pragma unroll
        for (int r = 0; r < 4; ++r) {
            int m = m0 + wm + i * 16 + q * 4 + r;
#pragma unroll
            for (int j = 0; j < 2; ++j) {
                int n = n0 + wn + j * 16 + li;
                float x = (acc[i][j][r] + bi[j]) * sc[j] + hh[j];
                out[(size_t)m * N + n] = (__bf16)fmaxf(x, 0.f);
            }
        }
    }
}

// ========= fused fc3 + bn + relu + out layer -> fp32 d_out ===================
__global__ __launch_bounds__(256) void k_fc3out(
    const __bf16* __restrict__ A, const __bf16* __restrict__ W3,
    const __bf16* __restrict__ Wo,
    const float* __restrict__ b3,
    const float* __restrict__ bng, const float* __restrict__ bnb,
    const float* __restrict__ bnm, const float* __restrict__ bnv,
    const float* __restrict__ bo, float* __restrict__ out) {
    const int t = threadIdx.x;
    const int lane = t & 63, w = t >> 6;
    const int q = lane >> 4, li = lane & 15;
    const int m0 = blockIdx.x * 64;
    const int wn = w * 32;

    __shared__ __align__(16) __bf16 As[64 * 40];
    __shared__ __align__(16) __bf16 Bs[128 * 40];
    __shared__ __align__(16) __bf16 ysb[64 * 136];

    const int rowA = (t & 127) >> 1, rowB = t >> 1, half = t & 1;
    const __bf16* Ag = A + (size_t)(m0 + rowA) * 512 + half * 16;
    const __bf16* Bg = W3 + (size_t)rowB * 512 + half * 16;

    f32x4 acc[4][2];
#pragma unroll
    for (int i = 0; i < 4; ++i)
#pragma unroll
        for (int j = 0; j < 2; ++j) acc[i][j] = (f32x4){0.f, 0.f, 0.f, 0.f};

    bf16x8 pa0, pa1, pb0, pb1;
    pb0 = *(const bf16x8*)Bg;
    pb1 = *(const bf16x8*)(Bg + 8);
    if (t < 128) {
        pa0 = *(const bf16x8*)Ag;
        pa1 = *(const bf16x8*)(Ag + 8);
    }
    for (int step = 0; step < 16; ++step) {
        if (t < 128) {
            *(bf16x8*)&As[rowA * 40 + half * 16] = pa0;
            *(bf16x8*)&As[rowA * 40 + half * 16 + 8] = pa1;
        }
        *(bf16x8*)&Bs[rowB * 40 + half * 16] = pb0;
        *(bf16x8*)&Bs[rowB * 40 + half * 16 + 8] = pb1;
        __syncthreads();
        Ag += 32; Bg += 32;
        if (step < 15) {
            pb0 = *(const bf16x8*)Bg;
            pb1 = *(const bf16x8*)(Bg + 8);
            if (t < 128) {
                pa0 = *(const bf16x8*)Ag;
                pa1 = *(const bf16x8*)(Ag + 8);
            }
        }
        bf16x8 af[4], bfr[2];
#pragma unroll
        for (int i = 0; i < 4; ++i)
            af[i] = *(const bf16x8*)&As[(i * 16 + li) * 40 + q * 8];
#pragma unroll
        for (int j = 0; j < 2; ++j)
            bfr[j] = *(const bf16x8*)&Bs[(wn + j * 16 + li) * 40 + q * 8];
#pragma unroll
        for (int i = 0; i < 4; ++i)
#pragma unroll
            for (int j = 0; j < 2; ++j)
                acc[i][j] = mfma16(af[i], bfr[j], acc[i][j]);
        __syncthreads();
    }
    {
#pragma unroll
        for (int j = 0; j < 2; ++j) {
            int n = wn + j * 16 + li;
            float sc = bng[n] * rsqrtf(bnv[n] + EPS);
            float hh = bnb[n] - bnm[n] * sc;
            float bi = b3[n];
#pragma unroll
            for (int i = 0; i < 4; ++i)
#pragma unroll
                for (int r = 0; r < 4; ++r) {
                    int ml = i * 16 + q * 4 + r;
                    float x = (acc[i][j][r] + bi) * sc + hh;
                    ysb[ml * 136 + n] = (__bf16)fmaxf(x, 0.f);
                }
        }
    }
    __syncthreads();
    f32x4 acc2[4][2];
#pragma unroll
    for (int i = 0; i < 4; ++i)
#pragma unroll
        for (int j = 0; j < 2; ++j) acc2[i][j] = (f32x4){0.f, 0.f, 0.f, 0.f};
    const __bf16* Bg2 = Wo + (size_t)rowB * 128 + half * 16;
#pragma unroll
    for (int step = 0; step < 4; ++step) {
        *(bf16x8*)&Bs[rowB * 40 + half * 16] = *(const bf16x8*)(Bg2 + step * 32);
        *(bf16x8*)&Bs[rowB * 40 + half * 16 + 8] = *(const bf16x8*)(Bg2 + step * 32 + 8);
        __syncthreads();
        bf16x8 af[4], bfr[2];
#pragma unroll
        for (int i = 0; i < 4; ++i)
            af[i] = *(const bf16x8*)&ysb[(i * 16 + li) * 136 + step * 32 + q * 8];
#pragma unroll
        for (int j = 0; j < 2; ++j)
            bfr[j] = *(const bf16x8*)&Bs[(wn + j * 16 + li) * 40 + q * 8];
#pragma unroll
        for (int i = 0; i < 4; ++i)
#pragma unroll
            for (int j = 0; j < 2; ++j)
                acc2[i][j] = mfma16(af[i], bfr[j], acc2[i][j]);
        __syncthreads();
    }
#pragma unroll
    for (int j = 0; j < 2; ++j) {
        int n = wn + j * 16 + li;
        float bi = bo[n];
#pragma unroll
        for (int i = 0; i < 4; ++i)
#pragma unroll
            for (int r = 0; r < 4; ++r) {
                int m = m0 + i * 16 + q * 4 + r;
                out[(size_t)m * 128 + n] = acc2[i][j][r] + bi;
            }
    }
}

extern "C" void kernel_launch(void* const* d_in, const int* in_sizes, int n_in,
                              void* d_out, int out_size, void* d_ws, size_t ws_size,
                              hipStream_t stream) {
    const float* inA    = (const float*)d_in[0];
    const float* inP    = (const float*)d_in[1];
    const float* inN    = (const float*)d_in[2];
    const float* bn0g   = (const float*)d_in[3];
    const float* bn0b   = (const float*)d_in[4];
    const float* bn0m   = (const float*)d_in[5];
    const float* bn0v   = (const float*)d_in[6];
    const float* conv1w = (const float*)d_in[7];
    const float* conv1b = (const float*)d_in[8];
    const float* bn1g   = (const float*)d_in[9];
    const float* bn1b   = (const float*)d_in[10];
    const float* bn1m   = (const float*)d_in[11];
    const float* bn1v   = (const float*)d_in[12];
    const float* conv2w = (const float*)d_in[13];
    const float* conv2b = (const float*)d_in[14];
    const float* bn2g   = (const float*)d_in[15];
    const float* bn2b   = (const float*)d_in[16];
    const float* bn2m   = (const float*)d_in[17];
    const float* bn2v   = (const float*)d_in[18];
    const float* lc1w   = (const float*)d_in[19];
    const float* bn3g   = (const float*)d_in[20];
    const float* bn3b   = (const float*)d_in[21];
    const float* bn3m   = (const float*)d_in[22];
    const float* bn3v   = (const float*)d_in[23];
    const float* lc2w   = (const float*)d_in[24];
    const float* bn4g   = (const float*)d_in[25];
    const float* bn4b   = (const float*)d_in[26];
    const float* bn4m   = (const float*)d_in[27];
    const float* bn4v   = (const float*)d_in[28];
    const float* fc1w   = (const float*)d_in[29];
    const float* fc1b   = (const float*)d_in[30];
    const float* bnf1g  = (const float*)d_in[31];
    const float* bnf1b  = (const float*)d_in[32];
    const float* bnf1m  = (const float*)d_in[33];
    const float* bnf1v  = (const float*)d_in[34];
    const float* fc2w   = (const float*)d_in[35];
    const float* fc2b   = (const float*)d_in[36];
    const float* bnf2g  = (const float*)d_in[37];
    const float* bnf2b  = (const float*)d_in[38];
    const float* bnf2m  = (const float*)d_in[39];
    const float* bnf2v  = (const float*)d_in[40];
    const float* fc3w   = (const float*)d_in[41];
    const float* fc3b   = (const float*)d_in[42];
    const float* bnf3g  = (const float*)d_in[43];
    const float* bnf3b  = (const float*)d_in[44];
    const float* bnf3m  = (const float*)d_in[45];
    const float* bnf3v  = (const float*)d_in[46];
    const float* outw   = (const float*)d_in[47];
    const float* outb   = (const float*)d_in[48];

    char* wsb = (char*)d_ws;
    __bf16* w1frag  = (__bf16*)wsb;                        // 2048 el
    __bf16* w2frag  = w1frag + 2048;                       // 36864 el
    __bf16* lc1frag = w2frag + 36864;                      // 524288 el
    __bf16* lc2frag = lc1frag + 524288;                    // 524288 el
    __bf16* fc1Wb   = lc2frag + 524288;                    // 4194304 el
    __bf16* wf23    = fc1Wb + 4194304;                     // 344064 el
    __bf16* act     = wf23 + 344064;                       // 12582912 el
    __bf16* act3    = act + 12582912;                      // 786432 el
    __bf16* act4    = act3 + 786432;                       // 786432 el
    float*  part    = (float*)(((uintptr_t)(act4 + 786432) + 15) & ~(uintptr_t)15);
    __bf16* wf2 = wf23;
    __bf16* wf3 = wf23 + 262144;
    __bf16* wfo = wf23 + 327680;

    // ---- K0: conv weight frags (needed by K1's conv blocks) ----
    k_prep_frags<<<19, 256, 0, stream>>>(conv1w, conv2w, w1frag, w2frag);

    // ---- K1: conv + overlapped big weight preps ----
    k_conv_mega<<<3520, 256, 0, stream>>>(inA, inP, inN,
        bn0g, bn0b, bn0m, bn0v, w1frag, conv1b, bn1g, bn1b, bn1m, bn1v,
        w2frag, conv2b, bn2g, bn2b, bn2m, bn2v, act,
        lc1w, lc2w, fc1w, fc2w, fc3w, outw,
        lc1frag, lc2frag, fc1Wb, wf23);

    // ---- K2: locally connected (in place), 128-sample tiles ----
    k_lc_mfma<<<dim3(128, 12), 256, 0, stream>>>(lc1frag, lc2frag,
        bn3g, bn3b, bn3m, bn3v, bn4g, bn4b, bn4m, bn4v, act);

    // ---- K3: fc1 (split-K 4, BK=64) + K4: reduce ----
    k_fc1_mfma<<<dim3(24, 8, 4), 256, 0, stream>>>(act, fc1Wb, part);
    k_fc1_reduce<<<768, 256, 0, stream>>>(part, fc1b, bnf1g, bnf1b, bnf1m, bnf1v, act3);

    // ---- K5: fc2 ----
    k_fc2_mfma<<<dim3(24, 8), 256, 0, stream>>>(act3, wf2, fc2b,
        bnf2g, bnf2b, bnf2m, bnf2v, act4);

    // ---- K6: fc3 + out fused ----
    k_fc3out<<<24, 256, 0, stream>>>(act4, wf3, wfo, fc3b,
        bnf3g, bnf3b, bnf3m, bnf3v, outb, (float*)d_out);
}